// Round 4
// baseline (1157.817 us; speedup 1.0000x reference)
//
#include <hip/hip_runtime.h>
#include <stdint.h>

#define ROWS 8192        // B*N
#define CAP 64           // per-(dir,expert) list cap: mean 20.5, sd 4.5 -> +9.6 sigma
#define NSTEPS 5
#define NBLK 256

typedef short bf16x8 __attribute__((ext_vector_type(8)));
typedef float f32x4 __attribute__((ext_vector_type(4)));
typedef unsigned short u16;
typedef unsigned int u32;

__device__ __forceinline__ float bf2f(u16 u){ union{u32 i; float f;} x; x.i=(u32)u<<16; return x.f; }
__device__ __forceinline__ u16 f2bf(float f){ union{float f; u32 i;} x; x.f=f; u32 r = x.i + 0x7fffu + ((x.i>>16)&1u); return (u16)(r>>16); }

#define MFMA __builtin_amdgcn_mfma_f32_16x16x32_bf16

// ---------------- prep ----------------

__device__ __forceinline__ float wsel(const float* __restrict__ Wr, const float* __restrict__ Wz,
                                      const float* __restrict__ Wh, int f, int o){
  if (o < 128) return Wr[(size_t)f*128 + o];
  if (o < 256) return Wz[(size_t)f*128 + (o-128)];
  return (f < 256) ? Wh[(size_t)f*128 + (o-256)] : 0.f;
}

// blocks [0,4096): init hf/hbf. blocks >=4096: fold weights. block 0 also zeroes the grid barrier.
__global__ void k_prep(const float* __restrict__ prop, float* __restrict__ hf, u16* __restrict__ hbf,
                       const float* __restrict__ W_in, const float* __restrict__ b_in,
                       const float* __restrict__ W_out, const float* __restrict__ b_out,
                       const float* __restrict__ W_r, const float* __restrict__ W_z,
                       const float* __restrict__ W_h,
                       u16* __restrict__ WfT, float* __restrict__ bv, u16* __restrict__ WhbT,
                       int* __restrict__ bar)
{
  int bid = blockIdx.x;
  if (bid == 0 && threadIdx.x < 2) bar[threadIdx.x] = 0;
  if (bid < 4096){
    int i = bid*256 + threadIdx.x;
    float v = prop[i]; hf[i] = v; hbf[i] = f2bf(v);
    return;
  }
  int i = (bid-4096)*256 + threadIdx.x;
  if (i < 640*384){                       // WfT[o][k], lanes over o (coalesced)
    int k = i/384, o = i - k*384;
    float s;
    if (k >= 512){
      s = wsel(W_r, W_z, W_h, 256 + (k-512), o);
    } else {
      const float* Wrow; int fb;
      if (k < 256){ Wrow = W_in  + (size_t)((k>>7)&1)*16384 + (size_t)(k&127)*128; fb = 0; }
      else { int kk = k-256; Wrow = W_out + (size_t)(kk>>7)*16384 + (size_t)(kk&127)*128; fb = 128; }
      s = 0.f;
#pragma unroll 8
      for (int f=0; f<128; f++) s += Wrow[f] * wsel(W_r, W_z, W_h, fb+f, o);
    }
    WfT[(size_t)o*640 + k] = f2bf(s);
  } else if (i < 640*384 + 4*384){
    int j = i - 640*384; int q = j / 384, o = j - q*384;
    const float* bp = (q < 2) ? (b_in + q*128) : (b_out + (q-2)*128);
    int fb = (q < 2) ? 0 : 128;
    float s = 0.f;
#pragma unroll 8
    for (int f=0; f<128; f++) s += bp[f] * wsel(W_r, W_z, W_h, fb+f, o);
    bv[j] = s;
  } else if (i < 640*384 + 4*384 + 128*128){
    int j = i - (640*384 + 4*384); int kk = j>>7, o = j&127;
    WhbT[(size_t)o*128 + kk] = f2bf(W_h[(size_t)(256+kk)*128 + o]);
  }
}

// CSR via block-local LDS lists
__global__ void k_csr(const float* __restrict__ A,
                      int* __restrict__ idx4, int* __restrict__ cnt4)
{
  __shared__ int scnt[4];
  __shared__ int slist[4][CAP];
  int row = blockIdx.x, tid = threadIdx.x;
  if (tid < 4) scnt[tid] = 0;
  __syncthreads();
  const float* ar = A + (size_t)row * 8192;
  for (int c = tid*4; c < 8192; c += 1024){
    float4 v = *reinterpret_cast<const float4*>(ar + c);
    float vv[4] = {v.x, v.y, v.z, v.w};
#pragma unroll
    for (int j=0;j<4;j++){
      if (vv[j] != 0.f){
        int m = c + j;
        int lst = ((m>>12)<<1) | (m&1);
        int n = (m & 4095) >> 1;
        int p = atomicAdd(&scnt[lst], 1);
        if (p < CAP) slist[lst][p] = n;
      }
    }
  }
  __syncthreads();
  if (tid < 4) cnt4[(row<<2) + tid] = scnt[tid];
  for (int j = tid; j < 4*CAP; j += 256){
    int l = j>>6, p = j&63;
    int c = scnt[l]; if (c > CAP) c = CAP;
    if (p < c) idx4[(((size_t)(row<<2) + l)<<6) + p] = slist[l][p];
  }
}

// ---------------- persistent all-steps kernel ----------------

__device__ __forceinline__ void grid_sync(int* bar){
  __syncthreads();
  if (threadIdx.x == 0){
    __threadfence();                               // publish this XCD's dirty lines (buffer_wbl2)
    int g = __hip_atomic_load(bar+1, __ATOMIC_RELAXED, __HIP_MEMORY_SCOPE_AGENT);
    int a = __hip_atomic_fetch_add(bar, 1, __ATOMIC_ACQ_REL, __HIP_MEMORY_SCOPE_AGENT);
    if (a == NBLK-1){
      __hip_atomic_store(bar,   0,   __ATOMIC_RELAXED, __HIP_MEMORY_SCOPE_AGENT);
      __hip_atomic_store(bar+1, g+1, __ATOMIC_RELEASE, __HIP_MEMORY_SCOPE_AGENT);
    } else {
      while (__hip_atomic_load(bar+1, __ATOMIC_ACQUIRE, __HIP_MEMORY_SCOPE_AGENT) == g)
        __builtin_amdgcn_s_sleep(2);
    }
    __threadfence();                               // invalidate stale cached lines (buffer_inv)
  }
  __syncthreads();
}

__global__ __launch_bounds__(512) void k_steps(
    const int* __restrict__ cnt4, const int* __restrict__ idx4,
    const u16* __restrict__ WfT, const float* __restrict__ bv,
    const float* __restrict__ b_r, const float* __restrict__ b_z, const float* __restrict__ b_h,
    const u16* __restrict__ WhbT, float* __restrict__ hf, u16* __restrict__ hbf,
    int* __restrict__ bar)
{
  __shared__ u16  X_s[32*512];       // gathered sums, XOR-swizzled rows (stride 1024B)
  __shared__ u16  rh_s[32*128];      // r*h, XOR-swizzled rows (stride 256B)
  __shared__ u16  z_s[32*128];       // z quantized u16 fixed-point
  __shared__ float hh_s[32][128];    // pre-tanh partial

  int tid  = threadIdx.x;
  int wave = tid>>6, lane = tid&63, lr = lane&15, lk = lane>>4;
  int m0 = blockIdx.x*32;
  size_t bbase = ((size_t)(m0>>11))<<18;      // batch base (elements) — 32 | 2048 so block is single-batch

  for (int step=0; step<NSTEPS; step++){
    // ---- gather: 128 lists, 16 per wave, 4 concurrent chains ----
    const u16* hb = hbf + bbase + (lane<<1);
    for (int g=0; g<4; g++){
      int l0 = wave*16 + g*4;
      float a0[4]={0,0,0,0}, a1[4]={0,0,0,0};
      int my[4], cc[4];
#pragma unroll
      for (int j=0;j<4;j++){
        int l = l0+j, rl = l>>2, q = l&3;
        int lid = ((m0+rl)<<2) | q;
        int c = cnt4[lid]; if (c > CAP) c = CAP;
        cc[j] = c;
        my[j] = (lane < c) ? idx4[((size_t)lid<<6) + lane] : 0;
      }
      int cmax = max(max(cc[0],cc[1]), max(cc[2],cc[3]));
      for (int i=0;i<cmax;i++){
        u32 v[4];
#pragma unroll
        for (int j=0;j<4;j++){
          int n = __shfl(my[j], i);
          v[j] = *reinterpret_cast<const u32*>(hb + ((size_t)n<<7));
        }
#pragma unroll
        for (int j=0;j<4;j++){
          if (i < cc[j]){
            a0[j] += bf2f((u16)(v[j] & 0xffffu));
            a1[j] += bf2f((u16)(v[j] >> 16));
          }
        }
      }
#pragma unroll
      for (int j=0;j<4;j++){
        int l = l0+j, rl = l>>2, q = l&3;
        u32 pk = ((u32)f2bf(a1[j])<<16) | (u32)f2bf(a0[j]);
        char* p = (char*)X_s + ((rl*1024 + q*256 + lane*4) ^ ((rl&7)<<4));
        *reinterpret_cast<u32*>(p) = pk;
      }
    }
    __syncthreads();

    // ---- GEMM1: pre[32x384] = [X_s | hbf] @ WfT^T ----
    int n0 = wave*48;
    f32x4 acc[2][3] = {};
    const u16* Bw = WfT + (size_t)(n0+lr)*640 + lk*8;
#pragma unroll
    for (int k=0;k<512;k+=32){
      bf16x8 b0 = *reinterpret_cast<const bf16x8*>(Bw + k);
      bf16x8 b1 = *reinterpret_cast<const bf16x8*>(Bw + 16*640 + k);
      bf16x8 b2 = *reinterpret_cast<const bf16x8*>(Bw + 32*640 + k);
#pragma unroll
      for (int mt=0;mt<2;mt++){
        int row = mt*16 + lr;
        const char* pa = (const char*)X_s + ((row*1024 + (k + lk*8)*2) ^ ((row&7)<<4));
        bf16x8 a = *reinterpret_cast<const bf16x8*>(pa);
        acc[mt][0] = MFMA(a, b0, acc[mt][0], 0,0,0);
        acc[mt][1] = MFMA(a, b1, acc[mt][1], 0,0,0);
        acc[mt][2] = MFMA(a, b2, acc[mt][2], 0,0,0);
      }
    }
#pragma unroll
    for (int k=0;k<128;k+=32){
      bf16x8 b0 = *reinterpret_cast<const bf16x8*>(Bw + 512 + k);
      bf16x8 b1 = *reinterpret_cast<const bf16x8*>(Bw + 16*640 + 512 + k);
      bf16x8 b2 = *reinterpret_cast<const bf16x8*>(Bw + 32*640 + 512 + k);
#pragma unroll
      for (int mt=0;mt<2;mt++){
        bf16x8 a = *reinterpret_cast<const bf16x8*>(hbf + (size_t)(m0+mt*16+lr)*128 + k + lk*8);
        acc[mt][0] = MFMA(a, b0, acc[mt][0], 0,0,0);
        acc[mt][1] = MFMA(a, b1, acc[mt][1], 0,0,0);
        acc[mt][2] = MFMA(a, b2, acc[mt][2], 0,0,0);
      }
    }

    // ---- epilogue 1 ----
#pragma unroll
    for (int nt=0;nt<3;nt++){
      int oo = n0 + nt*16 + lr;
      float base = (oo<128) ? b_r[oo] : (oo<256) ? b_z[oo-128] : b_h[oo-256];
      float q0 = bv[oo], q1 = bv[384+oo], q2 = bv[768+oo], q3 = bv[1152+oo];
#pragma unroll
      for (int mt=0;mt<2;mt++){
#pragma unroll
        for (int i2=0;i2<4;i2++){
          int rl = mt*16 + lk*4 + i2;
          const int* cp = cnt4 + ((m0+rl)<<2);
          float v = acc[mt][nt][i2] + base
                  + cp[0]*q0 + cp[1]*q1 + cp[2]*q2 + cp[3]*q3;
          if (oo < 128){
            float s = 1.f/(1.f + expf(-v));
            float hv = hf[(size_t)(m0+rl)*128 + oo];
            *reinterpret_cast<u16*>((char*)rh_s + ((rl*256 + oo*2) ^ ((rl&7)<<4))) = f2bf(s*hv);
          } else if (oo < 256){
            float s = 1.f/(1.f + expf(-v));
            z_s[rl*128 + (oo-128)] = (u16)(s*65535.f + 0.5f);
          } else {
            hh_s[rl][oo-256] = v;
          }
        }
      }
    }
    __syncthreads();

    // ---- GEMM2: H2[32x128] = rh_s @ WhbT^T + update ----
    int c0 = wave*16;
    f32x4 acc2[2] = {};
    const u16* Bh = WhbT + (size_t)(c0+lr)*128 + lk*8;
#pragma unroll
    for (int k=0;k<128;k+=32){
      bf16x8 b = *reinterpret_cast<const bf16x8*>(Bh + k);
#pragma unroll
      for (int mt=0;mt<2;mt++){
        int rr = mt*16 + lr;
        bf16x8 a = *reinterpret_cast<const bf16x8*>((char*)rh_s + ((rr*256 + (k + lk*8)*2) ^ ((rr&7)<<4)));
        acc2[mt] = MFMA(a, b, acc2[mt], 0,0,0);
      }
    }
#pragma unroll
    for (int mt=0;mt<2;mt++){
#pragma unroll
      for (int i2=0;i2<4;i2++){
        int rl = mt*16 + lk*4 + i2, col = c0 + lr;
        size_t ix = (size_t)(m0+rl)*128 + col;
        float hhat = tanhf(acc2[mt][i2] + hh_s[rl][col]);
        float zz = (float)z_s[rl*128 + col] * (1.f/65535.f);
        float ho = hf[ix];
        float hn = ho + zz*(hhat - ho);
        hf[ix] = hn;
        hbf[ix] = f2bf(hn);
      }
    }

    if (step < NSTEPS-1) grid_sync(bar);
    if (step < NSTEPS-1) __syncthreads();
  }
}

// ---------------- host ----------------

extern "C" void kernel_launch(void* const* d_in, const int* in_sizes, int n_in,
                              void* d_out, int out_size, void* d_ws, size_t ws_size,
                              hipStream_t stream)
{
  const float* prop  = (const float*)d_in[0];
  const float* A     = (const float*)d_in[1];
  const float* W_in  = (const float*)d_in[2];
  const float* b_in  = (const float*)d_in[3];
  const float* W_out = (const float*)d_in[4];
  const float* b_out = (const float*)d_in[5];
  const float* W_r   = (const float*)d_in[6];
  const float* b_r   = (const float*)d_in[7];
  const float* W_z   = (const float*)d_in[8];
  const float* b_z   = (const float*)d_in[9];
  const float* W_h   = (const float*)d_in[10];
  const float* b_h   = (const float*)d_in[11];

  char* ws = (char*)d_ws;
  size_t off = 0;
  auto nxt = [&](size_t bytes)->char*{ char* p = ws + off; off += (bytes + 255) & ~(size_t)255; return p; };
  int*   cnt4  = (int*)  nxt((size_t)ROWS*4*4);
  int*   idx4  = (int*)  nxt((size_t)ROWS*4*CAP*4);
  u16*   hbf   = (u16*)  nxt((size_t)ROWS*128*2);
  float* hf    = (float*)nxt((size_t)ROWS*128*4);
  u16*   WfT   = (u16*)  nxt((size_t)384*640*2);
  float* bv    = (float*)nxt((size_t)4*384*4);
  u16*   WhbT  = (u16*)  nxt((size_t)128*128*2);
  int*   bar   = (int*)  nxt(256);

  int fold_blocks = (640*384 + 4*384 + 128*128 + 255)/256;
  k_prep<<<4096 + fold_blocks, 256, 0, stream>>>(prop, hf, hbf,
      W_in, b_in, W_out, b_out, W_r, W_z, W_h, WfT, bv, WhbT, bar);
  k_csr<<<ROWS, 256, 0, stream>>>(A, idx4, cnt4);
  k_steps<<<NBLK, 512, 0, stream>>>(cnt4, idx4, WfT, bv, b_r, b_z, b_h, WhbT, hf, hbf, bar);

  hipMemcpyAsync(d_out, hf, (size_t)ROWS*128*4, hipMemcpyDeviceToDevice, stream);
}

// Round 5
// 349.137 us; speedup vs baseline: 3.3162x; 3.3162x over previous
//
#include <hip/hip_runtime.h>
#include <stdint.h>

#define ROWS 8192        // B*N
#define CAP 64           // per-(dir,expert) list cap: mean 20.5, sd 4.5 -> +9.6 sigma
#define NSTEPS 5
#define ZROW 8192        // sentinel: zeroed row appended to hbf

typedef short bf16x8 __attribute__((ext_vector_type(8)));
typedef float f32x4 __attribute__((ext_vector_type(4)));
typedef unsigned short u16;
typedef unsigned int u32;

__device__ __forceinline__ float bf2f(u16 u){ union{u32 i; float f;} x; x.i=(u32)u<<16; return x.f; }
__device__ __forceinline__ u16 f2bf(float f){ union{float f; u32 i;} x; x.f=f; u32 r = x.i + 0x7fffu + ((x.i>>16)&1u); return (u16)(r>>16); }

#define MFMA __builtin_amdgcn_mfma_f32_16x16x32_bf16
// rh LDS swizzle (G4): XOR row bits into 16B-slot bits to break stride-256B bank aliasing
#define SWZ(r, byte) ((byte) ^ (((r)&7)<<4))

// ---------------- prep ----------------

__device__ __forceinline__ float wsel(const float* __restrict__ Wr, const float* __restrict__ Wz,
                                      const float* __restrict__ Wh, int f, int o){
  if (o < 128) return Wr[(size_t)f*128 + o];
  if (o < 256) return Wz[(size_t)f*128 + (o-128)];
  return (f < 256) ? Wh[(size_t)f*128 + (o-256)] : 0.f;
}

// blocks [0,4096): init hf/hbf. blocks >=4096: fold weights. block 4096 zeroes the sentinel row.
__global__ void k_prep(const float* __restrict__ prop, float* __restrict__ hf, u16* __restrict__ hbf,
                       const float* __restrict__ W_in, const float* __restrict__ b_in,
                       const float* __restrict__ W_out, const float* __restrict__ b_out,
                       const float* __restrict__ W_r, const float* __restrict__ W_z,
                       const float* __restrict__ W_h,
                       u16* __restrict__ WfT, float* __restrict__ bv, u16* __restrict__ WhbT)
{
  int bid = blockIdx.x;
  if (bid < 4096){
    int i = bid*256 + threadIdx.x;
    float v = prop[i]; hf[i] = v; hbf[i] = f2bf(v);
    return;
  }
  if (bid == 4096 && threadIdx.x < 128) hbf[(size_t)ZROW*128 + threadIdx.x] = 0;  // sentinel row
  int i = (bid-4096)*256 + threadIdx.x;
  if (i < 640*384){                       // WfT[o][k], lanes over o (coalesced)
    int k = i/384, o = i - k*384;
    float s;
    if (k >= 512){
      s = wsel(W_r, W_z, W_h, 256 + (k-512), o);
    } else {
      const float* Wrow; int fb;
      if (k < 256){ Wrow = W_in  + (size_t)((k>>7)&1)*16384 + (size_t)(k&127)*128; fb = 0; }
      else { int kk = k-256; Wrow = W_out + (size_t)(kk>>7)*16384 + (size_t)(kk&127)*128; fb = 128; }
      s = 0.f;
#pragma unroll 8
      for (int f=0; f<128; f++) s += Wrow[f] * wsel(W_r, W_z, W_h, fb+f, o);
    }
    WfT[(size_t)o*640 + k] = f2bf(s);
  } else if (i < 640*384 + 4*384){
    int j = i - 640*384; int q = j / 384, o = j - q*384;
    const float* bp = (q < 2) ? (b_in + q*128) : (b_out + (q-2)*128);
    int fb = (q < 2) ? 0 : 128;
    float s = 0.f;
#pragma unroll 8
    for (int f=0; f<128; f++) s += bp[f] * wsel(W_r, W_z, W_h, fb+f, o);
    bv[j] = s;
  } else if (i < 640*384 + 4*384 + 128*128){
    int j = i - (640*384 + 4*384); int kk = j>>7, o = j&127;
    WhbT[(size_t)o*128 + kk] = f2bf(W_h[(size_t)(256+kk)*128 + o]);
  }
}

// CSR via block-local LDS lists; stores ABSOLUTE node index (batch*2048 + n)
__global__ void k_csr(const float* __restrict__ A,
                      int* __restrict__ idx4, int* __restrict__ cnt4)
{
  __shared__ int scnt[4];
  __shared__ int slist[4][CAP];
  int row = blockIdx.x, tid = threadIdx.x;
  if (tid < 4) scnt[tid] = 0;
  __syncthreads();
  const float* ar = A + (size_t)row * 8192;
  int babs = (row>>11)<<11;
  for (int c = tid*4; c < 8192; c += 1024){
    float4 v = *reinterpret_cast<const float4*>(ar + c);
    float vv[4] = {v.x, v.y, v.z, v.w};
#pragma unroll
    for (int j=0;j<4;j++){
      if (vv[j] != 0.f){
        int m = c + j;
        int lst = ((m>>12)<<1) | (m&1);
        int n = (m & 4095) >> 1;
        int p = atomicAdd(&scnt[lst], 1);
        if (p < CAP) slist[lst][p] = babs | n;
      }
    }
  }
  __syncthreads();
  if (tid < 4) cnt4[(row<<2) + tid] = scnt[tid];
  for (int j = tid; j < 4*CAP; j += 256){
    int l = j>>6, p = j&63;
    int c = scnt[l]; if (c > CAP) c = CAP;
    if (p < c) idx4[(((size_t)(row<<2) + l)<<6) + p] = slist[l][p];
  }
}

// ---------------- per-step kernels ----------------

// gather: block = 8 rows (32 lists), wave = 8 lists, 2-stage software pipeline, no predication
__global__ __launch_bounds__(256) void k_gather(const int* __restrict__ cnt4,
    const int* __restrict__ idx4, const u16* __restrict__ hbf, u16* __restrict__ X)
{
  int w = threadIdx.x>>6, lane = threadIdx.x&63;
  int m0 = blockIdx.x*8;
  int base_l = w*8;
  int cc[8], my[8];
#pragma unroll
  for (int j=0;j<8;j++){
    int l = base_l + j;
    int lid = ((m0 + (l>>2))<<2) | (l&3);
    int c = cnt4[lid]; if (c > CAP) c = CAP;
    cc[j] = c;
    my[j] = (lane < c) ? idx4[((size_t)lid<<6) + lane] : ZROW;
  }
  int cmax = 0;
#pragma unroll
  for (int j=0;j<8;j++) cmax = max(cmax, cc[j]);

  const u16* hb = hbf + (lane<<1);
  float a0[8] = {0,0,0,0,0,0,0,0}, a1[8] = {0,0,0,0,0,0,0,0};
  u32 v[8];
#pragma unroll
  for (int j=0;j<8;j++){                       // stage 0 loads (ZROW-safe even if cmax==0)
    int n = __shfl(my[j], 0);
    v[j] = *reinterpret_cast<const u32*>(hb + ((size_t)n<<7));
  }
  for (int i=1; i<cmax; i++){
    u32 vn[8];
#pragma unroll
    for (int j=0;j<8;j++){                     // issue iter i while iter i-1 is in flight
      int n = __shfl(my[j], i);
      vn[j] = *reinterpret_cast<const u32*>(hb + ((size_t)n<<7));
    }
#pragma unroll
    for (int j=0;j<8;j++){                     // consume iter i-1 (sentinel rows add 0)
      union{u32 u; float f;} lo, hi;
      lo.u = v[j]<<16; hi.u = v[j] & 0xffff0000u;
      a0[j] += lo.f; a1[j] += hi.f;
      v[j] = vn[j];
    }
  }
  if (cmax > 0){
#pragma unroll
    for (int j=0;j<8;j++){
      union{u32 u; float f;} lo, hi;
      lo.u = v[j]<<16; hi.u = v[j] & 0xffff0000u;
      a0[j] += lo.f; a1[j] += hi.f;
    }
  }
#pragma unroll
  for (int j=0;j<8;j++){
    int l = base_l + j, rl = l>>2, q = l&3;
    u32 pk = ((u32)f2bf(a1[j])<<16) | (u32)f2bf(a0[j]);
    *reinterpret_cast<u32*>(X + (size_t)(m0+rl)*512 + (q<<7) + (lane<<1)) = pk;
  }
}

// fused gates + final (verbatim R3 structure): block owns 32 rows; 8 waves
__global__ __launch_bounds__(512) void k_step(
    const u16* __restrict__ X, const u16* __restrict__ WfT, const float* __restrict__ bv,
    const int* __restrict__ cnt4,
    const float* __restrict__ b_r, const float* __restrict__ b_z, const float* __restrict__ b_h,
    const u16* __restrict__ WhbT, float* __restrict__ hf, u16* __restrict__ hbf)
{
  __shared__ u16  rh_s[32*128];      // swizzled bf16
  __shared__ u16  z_s[32*128];       // z as u16 fixed-point
  __shared__ float hh_s[32][128];
  __shared__ int  cnts[32][4];

  int tid = threadIdx.x;
  int wave = tid>>6, lane = tid&63, lr = lane&15, lk = lane>>4;
  int m0 = blockIdx.x*32;

  if (tid < 128) cnts[tid>>2][tid&3] = cnt4[((m0 + (tid>>2))<<2) + (tid&3)];
  __syncthreads();

  // ---- GEMM1: pre[32x384] = [X | hbf] @ WfT^T ----
  int n0 = wave*48;
  f32x4 acc[2][3] = {};
  const u16* Ax = X   + (size_t)(m0+lr)*512 + lk*8;
  const u16* Ah = hbf + (size_t)(m0+lr)*128 + lk*8;
  const u16* Bw = WfT + (size_t)(n0+lr)*640 + lk*8;
#pragma unroll
  for (int k=0;k<512;k+=32){
    bf16x8 b0 = *reinterpret_cast<const bf16x8*>(Bw + k);
    bf16x8 b1 = *reinterpret_cast<const bf16x8*>(Bw + 16*640 + k);
    bf16x8 b2 = *reinterpret_cast<const bf16x8*>(Bw + 32*640 + k);
#pragma unroll
    for (int mt=0;mt<2;mt++){
      bf16x8 a = *reinterpret_cast<const bf16x8*>(Ax + (size_t)mt*16*512 + k);
      acc[mt][0] = MFMA(a, b0, acc[mt][0], 0,0,0);
      acc[mt][1] = MFMA(a, b1, acc[mt][1], 0,0,0);
      acc[mt][2] = MFMA(a, b2, acc[mt][2], 0,0,0);
    }
  }
#pragma unroll
  for (int k=0;k<128;k+=32){
    bf16x8 b0 = *reinterpret_cast<const bf16x8*>(Bw + 512 + k);
    bf16x8 b1 = *reinterpret_cast<const bf16x8*>(Bw + 16*640 + 512 + k);
    bf16x8 b2 = *reinterpret_cast<const bf16x8*>(Bw + 32*640 + 512 + k);
#pragma unroll
    for (int mt=0;mt<2;mt++){
      bf16x8 a = *reinterpret_cast<const bf16x8*>(Ah + (size_t)mt*16*128 + k);
      acc[mt][0] = MFMA(a, b0, acc[mt][0], 0,0,0);
      acc[mt][1] = MFMA(a, b1, acc[mt][1], 0,0,0);
      acc[mt][2] = MFMA(a, b2, acc[mt][2], 0,0,0);
    }
  }

  // ---- epilogue 1 ----
#pragma unroll
  for (int nt=0;nt<3;nt++){
    int oo = n0 + nt*16 + lr;
    float base = (oo<128) ? b_r[oo] : (oo<256) ? b_z[oo-128] : b_h[oo-256];
    float q0 = bv[oo], q1 = bv[384+oo], q2 = bv[768+oo], q3 = bv[1152+oo];
#pragma unroll
    for (int mt=0;mt<2;mt++){
#pragma unroll
      for (int i2=0;i2<4;i2++){
        int rl = mt*16 + lk*4 + i2;
        float v = acc[mt][nt][i2] + base
                + cnts[rl][0]*q0 + cnts[rl][1]*q1 + cnts[rl][2]*q2 + cnts[rl][3]*q3;
        if (oo < 128){
          float s = 1.f/(1.f + expf(-v));
          float hv = hf[(size_t)(m0+rl)*128 + oo];
          *reinterpret_cast<u16*>((char*)rh_s + SWZ(rl, rl*256 + oo*2)) = f2bf(s*hv);
        } else if (oo < 256){
          float s = 1.f/(1.f + expf(-v));
          z_s[rl*128 + (oo-128)] = (u16)(s*65535.f + 0.5f);
        } else {
          hh_s[rl][oo-256] = v;
        }
      }
    }
  }
  __syncthreads();

  // ---- GEMM2: H2[32x128] = rh_s @ WhbT^T ----
  int c0 = wave*16;
  f32x4 acc2[2] = {};
  const u16* Bh = WhbT + (size_t)(c0+lr)*128 + lk*8;
#pragma unroll
  for (int k=0;k<128;k+=32){
    bf16x8 b = *reinterpret_cast<const bf16x8*>(Bh + k);
#pragma unroll
    for (int mt=0;mt<2;mt++){
      int rr = mt*16 + lr;
      bf16x8 a = *reinterpret_cast<const bf16x8*>((char*)rh_s + SWZ(rr, rr*256 + (k + lk*8)*2));
      acc2[mt] = MFMA(a, b, acc2[mt], 0,0,0);
    }
  }

  // ---- epilogue 2 ----
#pragma unroll
  for (int mt=0;mt<2;mt++){
#pragma unroll
    for (int i2=0;i2<4;i2++){
      int rl = mt*16 + lk*4 + i2, col = c0 + lr;
      size_t ix = (size_t)(m0+rl)*128 + col;
      float hhat = tanhf(acc2[mt][i2] + hh_s[rl][col]);
      float zz = (float)z_s[rl*128 + col] * (1.f/65535.f);
      float ho = hf[ix];
      float hn = ho + zz*(hhat - ho);
      hf[ix] = hn;
      hbf[ix] = f2bf(hn);
    }
  }
}

// ---------------- host ----------------

extern "C" void kernel_launch(void* const* d_in, const int* in_sizes, int n_in,
                              void* d_out, int out_size, void* d_ws, size_t ws_size,
                              hipStream_t stream)
{
  const float* prop  = (const float*)d_in[0];
  const float* A     = (const float*)d_in[1];
  const float* W_in  = (const float*)d_in[2];
  const float* b_in  = (const float*)d_in[3];
  const float* W_out = (const float*)d_in[4];
  const float* b_out = (const float*)d_in[5];
  const float* W_r   = (const float*)d_in[6];
  const float* b_r   = (const float*)d_in[7];
  const float* W_z   = (const float*)d_in[8];
  const float* b_z   = (const float*)d_in[9];
  const float* W_h   = (const float*)d_in[10];
  const float* b_h   = (const float*)d_in[11];

  char* ws = (char*)d_ws;
  size_t off = 0;
  auto nxt = [&](size_t bytes)->char*{ char* p = ws + off; off += (bytes + 255) & ~(size_t)255; return p; };
  int*   cnt4  = (int*)  nxt((size_t)ROWS*4*4);
  int*   idx4  = (int*)  nxt((size_t)ROWS*4*CAP*4);
  u16*   X     = (u16*)  nxt((size_t)ROWS*512*2);
  u16*   hbf   = (u16*)  nxt((size_t)(ROWS+1)*128*2);   // +1 sentinel zero row
  float* hf    = (float*)nxt((size_t)ROWS*128*4);
  u16*   WfT   = (u16*)  nxt((size_t)384*640*2);
  float* bv    = (float*)nxt((size_t)4*384*4);
  u16*   WhbT  = (u16*)  nxt((size_t)128*128*2);

  int fold_blocks = (640*384 + 4*384 + 128*128 + 255)/256;
  k_prep<<<4096 + fold_blocks, 256, 0, stream>>>(prop, hf, hbf,
      W_in, b_in, W_out, b_out, W_r, W_z, W_h, WfT, bv, WhbT);
  k_csr<<<ROWS, 256, 0, stream>>>(A, idx4, cnt4);

  for (int t=0; t<NSTEPS; t++){
    k_gather<<<ROWS/8, 256, 0, stream>>>(cnt4, idx4, hbf, X);
    k_step  <<<ROWS/32, 512, 0, stream>>>(X, WfT, bv, cnt4, b_r, b_z, b_h, WhbT, hf, hbf);
  }

  hipMemcpyAsync(d_out, hf, (size_t)ROWS*128*4, hipMemcpyDeviceToDevice, stream);
}

// Round 6
// 335.135 us; speedup vs baseline: 3.4548x; 1.0418x over previous
//
#include <hip/hip_runtime.h>
#include <stdint.h>

#define ROWS 8192        // B*N
#define CAP 64           // per-(dir,expert) list cap: mean 20.5, sd 4.5 -> +9.6 sigma
#define NSTEPS 5
#define ZROW 8192        // sentinel: zeroed row appended to hbf

typedef short bf16x8 __attribute__((ext_vector_type(8)));
typedef float f32x4 __attribute__((ext_vector_type(4)));
typedef unsigned short u16;
typedef unsigned int u32;

__device__ __forceinline__ float bf2f(u16 u){ union{u32 i; float f;} x; x.i=(u32)u<<16; return x.f; }
__device__ __forceinline__ u16 f2bf(float f){ union{float f; u32 i;} x; x.f=f; u32 r = x.i + 0x7fffu + ((x.i>>16)&1u); return (u16)(r>>16); }

#define MFMA __builtin_amdgcn_mfma_f32_16x16x32_bf16
// LDS swizzles (G4): XOR row bits into 16B-slot bits to break power-of-2 stride aliasing
#define SWZ(r, byte) ((byte) ^ (((r)&7)<<4))

// ---------------- prep ----------------

__device__ __forceinline__ float wsel(const float* __restrict__ Wr, const float* __restrict__ Wz,
                                      const float* __restrict__ Wh, int f, int o){
  if (o < 128) return Wr[(size_t)f*128 + o];
  if (o < 256) return Wz[(size_t)f*128 + (o-128)];
  return (f < 256) ? Wh[(size_t)f*128 + (o-256)] : 0.f;
}

// blocks [0,4096): init hf/hbf. blocks >=4096: fold weights. block 4096 zeroes the sentinel row.
__global__ void k_prep(const float* __restrict__ prop, float* __restrict__ hf, u16* __restrict__ hbf,
                       const float* __restrict__ W_in, const float* __restrict__ b_in,
                       const float* __restrict__ W_out, const float* __restrict__ b_out,
                       const float* __restrict__ W_r, const float* __restrict__ W_z,
                       const float* __restrict__ W_h,
                       u16* __restrict__ WfT, float* __restrict__ bv, u16* __restrict__ WhbT)
{
  int bid = blockIdx.x;
  if (bid < 4096){
    int i = bid*256 + threadIdx.x;
    float v = prop[i]; hf[i] = v; hbf[i] = f2bf(v);
    return;
  }
  if (bid == 4096 && threadIdx.x < 128) hbf[(size_t)ZROW*128 + threadIdx.x] = 0;  // sentinel row
  int i = (bid-4096)*256 + threadIdx.x;
  if (i < 640*384){                       // WfT[o][k], lanes over o (coalesced)
    int k = i/384, o = i - k*384;
    float s;
    if (k >= 512){
      s = wsel(W_r, W_z, W_h, 256 + (k-512), o);
    } else {
      const float* Wrow; int fb;
      if (k < 256){ Wrow = W_in  + (size_t)((k>>7)&1)*16384 + (size_t)(k&127)*128; fb = 0; }
      else { int kk = k-256; Wrow = W_out + (size_t)(kk>>7)*16384 + (size_t)(kk&127)*128; fb = 128; }
      s = 0.f;
#pragma unroll 8
      for (int f=0; f<128; f++) s += Wrow[f] * wsel(W_r, W_z, W_h, fb+f, o);
    }
    WfT[(size_t)o*640 + k] = f2bf(s);
  } else if (i < 640*384 + 4*384){
    int j = i - 640*384; int q = j / 384, o = j - q*384;
    const float* bp = (q < 2) ? (b_in + q*128) : (b_out + (q-2)*128);
    int fb = (q < 2) ? 0 : 128;
    float s = 0.f;
#pragma unroll 8
    for (int f=0; f<128; f++) s += bp[f] * wsel(W_r, W_z, W_h, fb+f, o);
    bv[j] = s;
  } else if (i < 640*384 + 4*384 + 128*128){
    int j = i - (640*384 + 4*384); int kk = j>>7, o = j&127;
    WhbT[(size_t)o*128 + kk] = f2bf(W_h[(size_t)(256+kk)*128 + o]);
  }
}

// CSR via block-local LDS lists; stores ABSOLUTE node index (batch*2048 + n)
__global__ void k_csr(const float* __restrict__ A,
                      int* __restrict__ idx4, int* __restrict__ cnt4)
{
  __shared__ int scnt[4];
  __shared__ int slist[4][CAP];
  int row = blockIdx.x, tid = threadIdx.x;
  if (tid < 4) scnt[tid] = 0;
  __syncthreads();
  const float* ar = A + (size_t)row * 8192;
  int babs = (row>>11)<<11;
  for (int c = tid*4; c < 8192; c += 1024){
    float4 v = *reinterpret_cast<const float4*>(ar + c);
    float vv[4] = {v.x, v.y, v.z, v.w};
#pragma unroll
    for (int j=0;j<4;j++){
      if (vv[j] != 0.f){
        int m = c + j;
        int lst = ((m>>12)<<1) | (m&1);
        int n = (m & 4095) >> 1;
        int p = atomicAdd(&scnt[lst], 1);
        if (p < CAP) slist[lst][p] = babs | n;
      }
    }
  }
  __syncthreads();
  if (tid < 4) cnt4[(row<<2) + tid] = scnt[tid];
  for (int j = tid; j < 4*CAP; j += 256){
    int l = j>>6, p = j&63;
    int c = scnt[l]; if (c > CAP) c = CAP;
    if (p < c) idx4[(((size_t)(row<<2) + l)<<6) + p] = slist[l][p];
  }
}

// ---------------- fused per-step kernel: gather (LDS) + GEMM1 + gates + GEMM2 + update ----------------
// block = 16 rows, 8 waves. Gather: 64 lists, 8/wave, one 8-wide pipelined pass.
// grid 512 blocks, 33 KB LDS -> 2 blocks/CU, 16 waves/CU.
__global__ __launch_bounds__(512) void k_fused(
    const int* __restrict__ cnt4, const int* __restrict__ idx4,
    const u16* __restrict__ WfT, const float* __restrict__ bv,
    const float* __restrict__ b_r, const float* __restrict__ b_z, const float* __restrict__ b_h,
    const u16* __restrict__ WhbT, float* __restrict__ hf, u16* __restrict__ hbf)
{
  __shared__ u16  X_s[16*512];       // gathered sums, swizzled rows (stride 1024B)
  __shared__ u16  rh_s[16*128];      // r*h, swizzled rows (stride 256B)
  __shared__ u16  z_s[16*128];       // z as u16 fixed-point
  __shared__ float hh_s[16][128];
  __shared__ int  cnts[16][4];

  int tid  = threadIdx.x;
  int wave = tid>>6, lane = tid&63, lr = lane&15, lk = lane>>4;
  int m0 = blockIdx.x*16;

  if (tid < 64) cnts[tid>>2][tid&3] = cnt4[((m0 + (tid>>2))<<2) + (tid&3)];

  // ---- gather: 8 lists per wave, 2-stage software pipeline, sentinel padding ----
  {
    int base_l = wave*8;
    int cc[8], my[8];
#pragma unroll
    for (int j=0;j<8;j++){
      int l = base_l + j;
      int lid = ((m0 + (l>>2))<<2) | (l&3);
      int c = cnt4[lid]; if (c > CAP) c = CAP;
      cc[j] = c;
      my[j] = (lane < c) ? idx4[((size_t)lid<<6) + lane] : ZROW;
    }
    int cmax = 0;
#pragma unroll
    for (int j=0;j<8;j++) cmax = max(cmax, cc[j]);

    const u16* hb = hbf + (lane<<1);
    float a0[8] = {0,0,0,0,0,0,0,0}, a1[8] = {0,0,0,0,0,0,0,0};
    u32 v[8];
#pragma unroll
    for (int j=0;j<8;j++){
      int n = __shfl(my[j], 0);
      v[j] = *reinterpret_cast<const u32*>(hb + ((size_t)n<<7));
    }
    for (int i=1; i<cmax; i++){
      u32 vn[8];
#pragma unroll
      for (int j=0;j<8;j++){
        int n = __shfl(my[j], i);
        vn[j] = *reinterpret_cast<const u32*>(hb + ((size_t)n<<7));
      }
#pragma unroll
      for (int j=0;j<8;j++){
        union{u32 u; float f;} lo, hi;
        lo.u = v[j]<<16; hi.u = v[j] & 0xffff0000u;
        a0[j] += lo.f; a1[j] += hi.f;
        v[j] = vn[j];
      }
    }
    if (cmax > 0){
#pragma unroll
      for (int j=0;j<8;j++){
        union{u32 u; float f;} lo, hi;
        lo.u = v[j]<<16; hi.u = v[j] & 0xffff0000u;
        a0[j] += lo.f; a1[j] += hi.f;
      }
    }
#pragma unroll
    for (int j=0;j<8;j++){
      int l = base_l + j, rl = l>>2, q = l&3;
      u32 pk = ((u32)f2bf(a1[j])<<16) | (u32)f2bf(a0[j]);
      *reinterpret_cast<u32*>((char*)X_s + SWZ(rl, rl*1024 + q*256 + lane*4)) = pk;
    }
  }
  __syncthreads();

  // ---- GEMM1: pre[16x384] = [X_s | hbf] @ WfT^T ; wave tile 16(m) x 48(n) ----
  int n0 = wave*48;
  f32x4 acc[3] = {};
  const u16* Ah = hbf + (size_t)(m0+lr)*128 + lk*8;
  const u16* Bw = WfT + (size_t)(n0+lr)*640 + lk*8;
#pragma unroll
  for (int k=0;k<512;k+=32){
    bf16x8 b0 = *reinterpret_cast<const bf16x8*>(Bw + k);
    bf16x8 b1 = *reinterpret_cast<const bf16x8*>(Bw + 16*640 + k);
    bf16x8 b2 = *reinterpret_cast<const bf16x8*>(Bw + 32*640 + k);
    bf16x8 a = *reinterpret_cast<const bf16x8*>((const char*)X_s + SWZ(lr, lr*1024 + (k + lk*8)*2));
    acc[0] = MFMA(a, b0, acc[0], 0,0,0);
    acc[1] = MFMA(a, b1, acc[1], 0,0,0);
    acc[2] = MFMA(a, b2, acc[2], 0,0,0);
  }
#pragma unroll
  for (int k=0;k<128;k+=32){
    bf16x8 b0 = *reinterpret_cast<const bf16x8*>(Bw + 512 + k);
    bf16x8 b1 = *reinterpret_cast<const bf16x8*>(Bw + 16*640 + 512 + k);
    bf16x8 b2 = *reinterpret_cast<const bf16x8*>(Bw + 32*640 + 512 + k);
    bf16x8 a = *reinterpret_cast<const bf16x8*>(Ah + k);
    acc[0] = MFMA(a, b0, acc[0], 0,0,0);
    acc[1] = MFMA(a, b1, acc[1], 0,0,0);
    acc[2] = MFMA(a, b2, acc[2], 0,0,0);
  }

  // ---- epilogue 1: r -> rh_s (swizzled), z -> z_s, hh -> hh_s ----
#pragma unroll
  for (int nt=0;nt<3;nt++){
    int oo = n0 + nt*16 + lr;
    float base = (oo<128) ? b_r[oo] : (oo<256) ? b_z[oo-128] : b_h[oo-256];
    float q0 = bv[oo], q1 = bv[384+oo], q2 = bv[768+oo], q3 = bv[1152+oo];
#pragma unroll
    for (int i2=0;i2<4;i2++){
      int rl = lk*4 + i2;
      float v = acc[nt][i2] + base
              + cnts[rl][0]*q0 + cnts[rl][1]*q1 + cnts[rl][2]*q2 + cnts[rl][3]*q3;
      if (oo < 128){
        float s = 1.f/(1.f + expf(-v));
        float hv = hf[(size_t)(m0+rl)*128 + oo];
        *reinterpret_cast<u16*>((char*)rh_s + SWZ(rl, rl*256 + oo*2)) = f2bf(s*hv);
      } else if (oo < 256){
        float s = 1.f/(1.f + expf(-v));
        z_s[rl*128 + (oo-128)] = (u16)(s*65535.f + 0.5f);
      } else {
        hh_s[rl][oo-256] = v;
      }
    }
  }
  __syncthreads();

  // ---- GEMM2: H2[16x128] = rh_s @ WhbT^T ; wave tile 16(m) x 16(n) ----
  int c0 = wave*16;
  f32x4 acc2 = {};
  const u16* Bh = WhbT + (size_t)(c0+lr)*128 + lk*8;
#pragma unroll
  for (int k=0;k<128;k+=32){
    bf16x8 b = *reinterpret_cast<const bf16x8*>(Bh + k);
    bf16x8 a = *reinterpret_cast<const bf16x8*>((char*)rh_s + SWZ(lr, lr*256 + (k + lk*8)*2));
    acc2 = MFMA(a, b, acc2, 0,0,0);
  }

  // ---- epilogue 2: h update ----
#pragma unroll
  for (int i2=0;i2<4;i2++){
    int rl = lk*4 + i2, col = c0 + lr;
    size_t ix = (size_t)(m0+rl)*128 + col;
    float hhat = tanhf(acc2[i2] + hh_s[rl][col]);
    float zz = (float)z_s[rl*128 + col] * (1.f/65535.f);
    float ho = hf[ix];
    float hn = ho + zz*(hhat - ho);
    hf[ix] = hn;
    hbf[ix] = f2bf(hn);
  }
}

// ---------------- host ----------------

extern "C" void kernel_launch(void* const* d_in, const int* in_sizes, int n_in,
                              void* d_out, int out_size, void* d_ws, size_t ws_size,
                              hipStream_t stream)
{
  const float* prop  = (const float*)d_in[0];
  const float* A     = (const float*)d_in[1];
  const float* W_in  = (const float*)d_in[2];
  const float* b_in  = (const float*)d_in[3];
  const float* W_out = (const float*)d_in[4];
  const float* b_out = (const float*)d_in[5];
  const float* W_r   = (const float*)d_in[6];
  const float* b_r   = (const float*)d_in[7];
  const float* W_z   = (const float*)d_in[8];
  const float* b_z   = (const float*)d_in[9];
  const float* W_h   = (const float*)d_in[10];
  const float* b_h   = (const float*)d_in[11];

  char* ws = (char*)d_ws;
  size_t off = 0;
  auto nxt = [&](size_t bytes)->char*{ char* p = ws + off; off += (bytes + 255) & ~(size_t)255; return p; };
  int*   cnt4  = (int*)  nxt((size_t)ROWS*4*4);
  int*   idx4  = (int*)  nxt((size_t)ROWS*4*CAP*4);
  u16*   hbf   = (u16*)  nxt((size_t)(ROWS+1)*128*2);   // +1 sentinel zero row
  float* hf    = (float*)nxt((size_t)ROWS*128*4);
  u16*   WfT   = (u16*)  nxt((size_t)384*640*2);
  float* bv    = (float*)nxt((size_t)4*384*4);
  u16*   WhbT  = (u16*)  nxt((size_t)128*128*2);

  int fold_blocks = (640*384 + 4*384 + 128*128 + 255)/256;
  k_prep<<<4096 + fold_blocks, 256, 0, stream>>>(prop, hf, hbf,
      W_in, b_in, W_out, b_out, W_r, W_z, W_h, WfT, bv, WhbT);
  k_csr<<<ROWS, 256, 0, stream>>>(A, idx4, cnt4);

  for (int t=0; t<NSTEPS; t++){
    k_fused<<<ROWS/16, 512, 0, stream>>>(cnt4, idx4, WfT, bv, b_r, b_z, b_h, WhbT, hf, hbf);
  }

  hipMemcpyAsync(d_out, hf, (size_t)ROWS*128*4, hipMemcpyDeviceToDevice, stream);
}

// Round 7
// 334.165 us; speedup vs baseline: 3.4648x; 1.0029x over previous
//
#include <hip/hip_runtime.h>
#include <stdint.h>

#define ROWS 8192        // B*N
#define CAP 64           // per-(dir,expert) list cap: mean 20.5, sd 4.5 -> +9.6 sigma
#define NSTEPS 5
#define ZROW 8192        // sentinel: zeroed row appended to hbf

typedef short bf16x8 __attribute__((ext_vector_type(8)));
typedef float f32x4 __attribute__((ext_vector_type(4)));
typedef unsigned short u16;
typedef unsigned int u32;

__device__ __forceinline__ float bf2f(u16 u){ union{u32 i; float f;} x; x.i=(u32)u<<16; return x.f; }
__device__ __forceinline__ u16 f2bf(float f){ union{float f; u32 i;} x; x.f=f; u32 r = x.i + 0x7fffu + ((x.i>>16)&1u); return (u16)(r>>16); }

#define MFMA __builtin_amdgcn_mfma_f32_16x16x32_bf16
// LDS swizzle (G4): XOR row bits into 16B-slot bits to break power-of-2 stride aliasing
#define SWZ(r, byte) ((byte) ^ (((r)&7)<<4))

// ---------------- prep ----------------

__device__ __forceinline__ float wsel(const float* __restrict__ Wr, const float* __restrict__ Wz,
                                      const float* __restrict__ Wh, int f, int o){
  if (o < 128) return Wr[(size_t)f*128 + o];
  if (o < 256) return Wz[(size_t)f*128 + (o-128)];
  return (f < 256) ? Wh[(size_t)f*128 + (o-256)] : 0.f;
}

// blocks [0,4096): init hf/hbf. blocks >=4096: fold weights. block 4096 zeroes the sentinel row.
__global__ void k_prep(const float* __restrict__ prop, float* __restrict__ hf, u16* __restrict__ hbf,
                       const float* __restrict__ W_in, const float* __restrict__ b_in,
                       const float* __restrict__ W_out, const float* __restrict__ b_out,
                       const float* __restrict__ W_r, const float* __restrict__ W_z,
                       const float* __restrict__ W_h,
                       u16* __restrict__ WfT, float* __restrict__ bv, u16* __restrict__ WhbT)
{
  int bid = blockIdx.x;
  if (bid < 4096){
    int i = bid*256 + threadIdx.x;
    float v = prop[i]; hf[i] = v; hbf[i] = f2bf(v);
    return;
  }
  if (bid == 4096 && threadIdx.x < 128) hbf[(size_t)ZROW*128 + threadIdx.x] = 0;  // sentinel row
  int i = (bid-4096)*256 + threadIdx.x;
  if (i < 640*384){                       // WfT[o][k], lanes over o (coalesced)
    int k = i/384, o = i - k*384;
    float s;
    if (k >= 512){
      s = wsel(W_r, W_z, W_h, 256 + (k-512), o);
    } else {
      const float* Wrow; int fb;
      if (k < 256){ Wrow = W_in  + (size_t)((k>>7)&1)*16384 + (size_t)(k&127)*128; fb = 0; }
      else { int kk = k-256; Wrow = W_out + (size_t)(kk>>7)*16384 + (size_t)(kk&127)*128; fb = 128; }
      s = 0.f;
#pragma unroll 8
      for (int f=0; f<128; f++) s += Wrow[f] * wsel(W_r, W_z, W_h, fb+f, o);
    }
    WfT[(size_t)o*640 + k] = f2bf(s);
  } else if (i < 640*384 + 4*384){
    int j = i - 640*384; int q = j / 384, o = j - q*384;
    const float* bp = (q < 2) ? (b_in + q*128) : (b_out + (q-2)*128);
    int fb = (q < 2) ? 0 : 128;
    float s = 0.f;
#pragma unroll 8
    for (int f=0; f<128; f++) s += bp[f] * wsel(W_r, W_z, W_h, fb+f, o);
    bv[j] = s;
  } else if (i < 640*384 + 4*384 + 128*128){
    int j = i - (640*384 + 4*384); int kk = j>>7, o = j&127;
    WhbT[(size_t)o*128 + kk] = f2bf(W_h[(size_t)(256+kk)*128 + o]);
  }
}

// CSR via block-local LDS lists; stores ABSOLUTE node index (batch*2048 + n)
__global__ void k_csr(const float* __restrict__ A,
                      int* __restrict__ idx4, int* __restrict__ cnt4)
{
  __shared__ int scnt[4];
  __shared__ int slist[4][CAP];
  int row = blockIdx.x, tid = threadIdx.x;
  if (tid < 4) scnt[tid] = 0;
  __syncthreads();
  const float* ar = A + (size_t)row * 8192;
  int babs = (row>>11)<<11;
  for (int c = tid*4; c < 8192; c += 1024){
    float4 v = *reinterpret_cast<const float4*>(ar + c);
    float vv[4] = {v.x, v.y, v.z, v.w};
#pragma unroll
    for (int j=0;j<4;j++){
      if (vv[j] != 0.f){
        int m = c + j;
        int lst = ((m>>12)<<1) | (m&1);
        int n = (m & 4095) >> 1;
        int p = atomicAdd(&scnt[lst], 1);
        if (p < CAP) slist[lst][p] = babs | n;
      }
    }
  }
  __syncthreads();
  if (tid < 4) cnt4[(row<<2) + tid] = scnt[tid];
  for (int j = tid; j < 4*CAP; j += 256){
    int l = j>>6, p = j&63;
    int c = scnt[l]; if (c > CAP) c = CAP;
    if (p < c) idx4[(((size_t)(row<<2) + l)<<6) + p] = slist[l][p];
  }
}

// ---------------- fused per-step kernel: 32 rows/block, 256 blocks ----------------
// gather: 128 lists, 2 passes x (8 waves x 8 lists), R6's pipelined loop.
// GEMM1: wave tile 32m x 48n (R5 tiling), A from swizzled X_s + hbf, B streamed from WfT.
// LDS 56.5 KB -> 2 blocks/CU (16 waves/CU).
__global__ __launch_bounds__(512) void k_fused(
    const int* __restrict__ cnt4, const int* __restrict__ idx4,
    const u16* __restrict__ WfT, const float* __restrict__ bv,
    const float* __restrict__ b_r, const float* __restrict__ b_z, const float* __restrict__ b_h,
    const u16* __restrict__ WhbT, float* __restrict__ hf, u16* __restrict__ hbf)
{
  __shared__ u16  X_s[32*512];       // gathered sums, swizzled rows (stride 1024B)
  __shared__ u16  rh_s[32*128];      // r*h, swizzled rows (stride 256B)
  __shared__ u16  z_s[32*128];       // z as u16 fixed-point
  __shared__ u16  hh_s[32*128];      // pre-tanh partial, bf16
  __shared__ int  cnts[32][4];

  int tid  = threadIdx.x;
  int wave = tid>>6, lane = tid&63, lr = lane&15, lk = lane>>4;
  int m0 = blockIdx.x*32;

  if (tid < 128) cnts[tid>>2][tid&3] = cnt4[((m0 + (tid>>2))<<2) + (tid&3)];

  // ---- gather: 2 passes x 8 lists/wave, 2-stage software pipeline, sentinel padding ----
  const u16* hb = hbf + (lane<<1);
#pragma unroll
  for (int p=0; p<2; p++){
    int base_l = p*64 + wave*8;
    int cc[8], my[8];
#pragma unroll
    for (int j=0;j<8;j++){
      int l = base_l + j;
      int lid = ((m0 + (l>>2))<<2) | (l&3);
      int c = cnt4[lid]; if (c > CAP) c = CAP;
      cc[j] = c;
      my[j] = (lane < c) ? idx4[((size_t)lid<<6) + lane] : ZROW;
    }
    int cmax = 0;
#pragma unroll
    for (int j=0;j<8;j++) cmax = max(cmax, cc[j]);

    float a0[8] = {0,0,0,0,0,0,0,0}, a1[8] = {0,0,0,0,0,0,0,0};
    u32 v[8];
#pragma unroll
    for (int j=0;j<8;j++){
      int n = __shfl(my[j], 0);
      v[j] = *reinterpret_cast<const u32*>(hb + ((size_t)n<<7));
    }
    for (int i=1; i<cmax; i++){
      u32 vn[8];
#pragma unroll
      for (int j=0;j<8;j++){
        int n = __shfl(my[j], i);
        vn[j] = *reinterpret_cast<const u32*>(hb + ((size_t)n<<7));
      }
#pragma unroll
      for (int j=0;j<8;j++){
        union{u32 u; float f;} lo, hi;
        lo.u = v[j]<<16; hi.u = v[j] & 0xffff0000u;
        a0[j] += lo.f; a1[j] += hi.f;
        v[j] = vn[j];
      }
    }
    if (cmax > 0){
#pragma unroll
      for (int j=0;j<8;j++){
        union{u32 u; float f;} lo, hi;
        lo.u = v[j]<<16; hi.u = v[j] & 0xffff0000u;
        a0[j] += lo.f; a1[j] += hi.f;
      }
    }
#pragma unroll
    for (int j=0;j<8;j++){
      int l = base_l + j, rl = l>>2, q = l&3;
      u32 pk = ((u32)f2bf(a1[j])<<16) | (u32)f2bf(a0[j]);
      *reinterpret_cast<u32*>((char*)X_s + SWZ(rl, rl*1024 + q*256 + lane*4)) = pk;
    }
  }
  __syncthreads();

  // ---- GEMM1: pre[32x384] = [X_s | hbf] @ WfT^T ; wave tile 32(m) x 48(n) ----
  int n0 = wave*48;
  f32x4 acc[2][3] = {};
  const u16* Ah = hbf + (size_t)(m0+lr)*128 + lk*8;
  const u16* Bw = WfT + (size_t)(n0+lr)*640 + lk*8;
#pragma unroll
  for (int k=0;k<512;k+=32){
    bf16x8 b0 = *reinterpret_cast<const bf16x8*>(Bw + k);
    bf16x8 b1 = *reinterpret_cast<const bf16x8*>(Bw + 16*640 + k);
    bf16x8 b2 = *reinterpret_cast<const bf16x8*>(Bw + 32*640 + k);
#pragma unroll
    for (int mt=0;mt<2;mt++){
      int row = mt*16 + lr;
      bf16x8 a = *reinterpret_cast<const bf16x8*>((const char*)X_s + SWZ(row, row*1024 + (k + lk*8)*2));
      acc[mt][0] = MFMA(a, b0, acc[mt][0], 0,0,0);
      acc[mt][1] = MFMA(a, b1, acc[mt][1], 0,0,0);
      acc[mt][2] = MFMA(a, b2, acc[mt][2], 0,0,0);
    }
  }
#pragma unroll
  for (int k=0;k<128;k+=32){
    bf16x8 b0 = *reinterpret_cast<const bf16x8*>(Bw + 512 + k);
    bf16x8 b1 = *reinterpret_cast<const bf16x8*>(Bw + 16*640 + 512 + k);
    bf16x8 b2 = *reinterpret_cast<const bf16x8*>(Bw + 32*640 + 512 + k);
#pragma unroll
    for (int mt=0;mt<2;mt++){
      bf16x8 a = *reinterpret_cast<const bf16x8*>(Ah + (size_t)mt*16*128 + k);
      acc[mt][0] = MFMA(a, b0, acc[mt][0], 0,0,0);
      acc[mt][1] = MFMA(a, b1, acc[mt][1], 0,0,0);
      acc[mt][2] = MFMA(a, b2, acc[mt][2], 0,0,0);
    }
  }

  // ---- epilogue 1: r -> rh_s (swizzled), z -> z_s, hh -> hh_s (bf16) ----
#pragma unroll
  for (int nt=0;nt<3;nt++){
    int oo = n0 + nt*16 + lr;
    float base = (oo<128) ? b_r[oo] : (oo<256) ? b_z[oo-128] : b_h[oo-256];
    float q0 = bv[oo], q1 = bv[384+oo], q2 = bv[768+oo], q3 = bv[1152+oo];
#pragma unroll
    for (int mt=0;mt<2;mt++){
#pragma unroll
      for (int i2=0;i2<4;i2++){
        int rl = mt*16 + lk*4 + i2;
        float v = acc[mt][nt][i2] + base
                + cnts[rl][0]*q0 + cnts[rl][1]*q1 + cnts[rl][2]*q2 + cnts[rl][3]*q3;
        if (oo < 128){
          float s = 1.f/(1.f + expf(-v));
          float hv = hf[(size_t)(m0+rl)*128 + oo];
          *reinterpret_cast<u16*>((char*)rh_s + SWZ(rl, rl*256 + oo*2)) = f2bf(s*hv);
        } else if (oo < 256){
          float s = 1.f/(1.f + expf(-v));
          z_s[rl*128 + (oo-128)] = (u16)(s*65535.f + 0.5f);
        } else {
          hh_s[rl*128 + (oo-256)] = f2bf(v);
        }
      }
    }
  }
  __syncthreads();

  // ---- GEMM2: H2[32x128] = rh_s @ WhbT^T ; wave tile 32(m) x 16(n) ----
  int c0 = wave*16;
  f32x4 acc2[2] = {};
  const u16* Bh = WhbT + (size_t)(c0+lr)*128 + lk*8;
#pragma unroll
  for (int k=0;k<128;k+=32){
    bf16x8 b = *reinterpret_cast<const bf16x8*>(Bh + k);
#pragma unroll
    for (int mt=0;mt<2;mt++){
      int rr = mt*16 + lr;
      bf16x8 a = *reinterpret_cast<const bf16x8*>((char*)rh_s + SWZ(rr, rr*256 + (k + lk*8)*2));
      acc2[mt] = MFMA(a, b, acc2[mt], 0,0,0);
    }
  }

  // ---- epilogue 2: h update ----
#pragma unroll
  for (int mt=0;mt<2;mt++){
#pragma unroll
    for (int i2=0;i2<4;i2++){
      int rl = mt*16 + lk*4 + i2, col = c0 + lr;
      size_t ix = (size_t)(m0+rl)*128 + col;
      float hhat = tanhf(acc2[mt][i2] + bf2f(hh_s[rl*128 + col]));
      float zz = (float)z_s[rl*128 + col] * (1.f/65535.f);
      float ho = hf[ix];
      float hn = ho + zz*(hhat - ho);
      hf[ix] = hn;
      hbf[ix] = f2bf(hn);
    }
  }
}

// ---------------- host ----------------

extern "C" void kernel_launch(void* const* d_in, const int* in_sizes, int n_in,
                              void* d_out, int out_size, void* d_ws, size_t ws_size,
                              hipStream_t stream)
{
  const float* prop  = (const float*)d_in[0];
  const float* A     = (const float*)d_in[1];
  const float* W_in  = (const float*)d_in[2];
  const float* b_in  = (const float*)d_in[3];
  const float* W_out = (const float*)d_in[4];
  const float* b_out = (const float*)d_in[5];
  const float* W_r   = (const float*)d_in[6];
  const float* b_r   = (const float*)d_in[7];
  const float* W_z   = (const float*)d_in[8];
  const float* b_z   = (const float*)d_in[9];
  const float* W_h   = (const float*)d_in[10];
  const float* b_h   = (const float*)d_in[11];

  char* ws = (char*)d_ws;
  size_t off = 0;
  auto nxt = [&](size_t bytes)->char*{ char* p = ws + off; off += (bytes + 255) & ~(size_t)255; return p; };
  int*   cnt4  = (int*)  nxt((size_t)ROWS*4*4);
  int*   idx4  = (int*)  nxt((size_t)ROWS*4*CAP*4);
  u16*   hbf   = (u16*)  nxt((size_t)(ROWS+1)*128*2);   // +1 sentinel zero row
  float* hf    = (float*)nxt((size_t)ROWS*128*4);
  u16*   WfT   = (u16*)  nxt((size_t)384*640*2);
  float* bv    = (float*)nxt((size_t)4*384*4);
  u16*   WhbT  = (u16*)  nxt((size_t)128*128*2);

  int fold_blocks = (640*384 + 4*384 + 128*128 + 255)/256;
  k_prep<<<4096 + fold_blocks, 256, 0, stream>>>(prop, hf, hbf,
      W_in, b_in, W_out, b_out, W_r, W_z, W_h, WfT, bv, WhbT);
  k_csr<<<ROWS, 256, 0, stream>>>(A, idx4, cnt4);

  for (int t=0; t<NSTEPS; t++){
    k_fused<<<ROWS/32, 512, 0, stream>>>(cnt4, idx4, WfT, bv, b_r, b_z, b_h, WhbT, hf, hbf);
  }

  hipMemcpyAsync(d_out, hf, (size_t)ROWS*128*4, hipMemcpyDeviceToDevice, stream);
}